// Round 1
// baseline (232.696 us; speedup 1.0000x reference)
//
#include <hip/hip_runtime.h>

// LengthRegulator: B=32, T=512, D=384, ML=4096 (fixed by setup_inputs).
// out[b,f,:] = (f < total_b) ? x[b, searchsorted(cum_b, f, 'right').clip(0,T-1), :] : 0
// mel_pos[b,f] = (f < total_b) ? f+1 : 0   -- written as FLOAT values (harness
// reads the whole concatenated d_out as float32).

constexpr int B  = 32;
constexpr int T  = 512;
constexpr int D  = 384;
constexpr int ML = 4096;
constexpr int D4 = D / 4;            // 96 float4 per row
constexpr int FPB = 128;             // frames per block
constexpr int BLOCKS_PER_BATCH = ML / FPB;   // 32
constexpr int NT = 256;              // threads per block

__global__ __launch_bounds__(NT) void lr_kernel(
        const float4* __restrict__ x,      // [B, T, D4]
        const int*    __restrict__ dur,    // [B, T]
        float*        __restrict__ outf,   // [B, ML, D] then mel at +B*ML*D
        float*        __restrict__ mel)    // [B, ML]
{
    __shared__ int s_cum[T];
    __shared__ int s_tok[FPB];
    __shared__ int s_part[NT];

    const int b      = blockIdx.x / BLOCKS_PER_BATCH;
    const int fchunk = blockIdx.x % BLOCKS_PER_BATCH;
    const int f0     = fchunk * FPB;
    const int tid    = threadIdx.x;

    // ---- cumsum(duration[b]) into LDS (each thread owns 2 elements) ----
    const int d0 = dur[b * T + 2 * tid];
    const int d1 = dur[b * T + 2 * tid + 1];
    const int pair = d0 + d1;
    s_part[tid] = pair;
    __syncthreads();
    int val = pair;
    #pragma unroll
    for (int off = 1; off < NT; off <<= 1) {
        int t = (tid >= off) ? s_part[tid - off] : 0;
        __syncthreads();
        val += t;
        s_part[tid] = val;
        __syncthreads();
    }
    const int excl = val - pair;          // exclusive scan of pair-sums
    s_cum[2 * tid]     = excl + d0;
    s_cum[2 * tid + 1] = excl + pair;
    __syncthreads();
    const int total = s_cum[T - 1];

    // ---- token index for this block's FPB frames (binary search in LDS) ----
    if (tid < FPB) {
        const int f = f0 + tid;
        int lo = 0, hi = T;               // searchsorted(side='right')
        while (lo < hi) {
            const int mid = (lo + hi) >> 1;
            if (s_cum[mid] <= f) lo = mid + 1; else hi = mid;
        }
        const int tok = (lo < T - 1) ? lo : (T - 1);
        s_tok[tid] = (f < total) ? tok : -1;
        mel[b * ML + f] = (f < total) ? (float)(f + 1) : 0.0f;
    }
    __syncthreads();

    // ---- coalesced float4 copy: FPB*D4 = 12288 vec4 per block ----
    float4* __restrict__ out4 = (float4*)outf;
    const float4 zero4 = make_float4(0.f, 0.f, 0.f, 0.f);
    const size_t out_base = ((size_t)b * ML + f0) * D4;
    const size_t x_base   = (size_t)b * T * D4;
    #pragma unroll 4
    for (int i = tid; i < FPB * D4; i += NT) {
        const int lf  = i / D4;
        const int c   = i - lf * D4;
        const int tok = s_tok[lf];
        float4 v = zero4;
        if (tok >= 0) v = x[x_base + (size_t)tok * D4 + c];
        out4[out_base + (size_t)lf * D4 + c] = v;
    }
}

extern "C" void kernel_launch(void* const* d_in, const int* in_sizes, int n_in,
                              void* d_out, int out_size, void* d_ws, size_t ws_size,
                              hipStream_t stream) {
    const float4* x   = (const float4*)d_in[0];
    const int*    dur = (const int*)d_in[1];
    float* outf = (float*)d_out;
    float* mel  = outf + (size_t)B * ML * D;   // mel_pos region, float values

    dim3 grid(B * BLOCKS_PER_BATCH);
    dim3 block(NT);
    lr_kernel<<<grid, block, 0, stream>>>(x, dur, outf, mel);
}